// Round 8
// baseline (473.765 us; speedup 1.0000x reference)
//
#include <hip/hip_runtime.h>
#include <stdint.h>
#include <stddef.h>

// snnLinear: FWHT -> A4 global asym fake-quant -> W4 per-row sym fake-quant
// -> linear.  out[m,n] = sx*sw[n] * sum_k (qx-zp)*qw + bias[n], exact in i32.
//
// R3: generic-pointer LDS -> scratch spill (197us/pass).
// R6: shfl-FWHT ~140us/pass: 384 ds_bpermute/wave is DS-pipe/latency bound.
// R8: FWHT_4096 = H64(a) x H64(b). Both H64s in-register; ONE LDS
//     transpose between (80 DS instrs/wave vs 384 bpermutes). GEMM keeps
//     the R7 swizzle (bank conflicts measured 0).

typedef __attribute__((ext_vector_type(4))) int int4v;
typedef __attribute__((ext_vector_type(4))) float float4v;

#define EPSQ 1e-8f

// In-register H64, descending strides 32..1 over index bits of j.
__device__ __forceinline__ void h64(float (&e)[64]) {
#pragma unroll
    for (int s = 32; s >= 1; s >>= 1)
#pragma unroll
        for (int j = 0; j < 64; ++j)
            if ((j & s) == 0) {
                float a = e[j], b = e[j + s];
                e[j] = a + b;
                e[j + s] = a - b;
            }
}

// ---- pass 1: FWHT (a-axis in-reg, LDS transpose, b-axis in-reg) ----------
// Element i = a*64 + b. Reference order = bits 11..0 descending:
// H64 over a (strides 2048..64) THEN H64 over b (strides 32..1).
__global__ __launch_bounds__(256) void k_fwht(
    const float* __restrict__ x, float* __restrict__ y,
    float2* __restrict__ wmm) {
    __shared__ float tile[4][4096];  // 16 KB per wave, disjoint
    int l = threadIdx.x & 63, w = threadIdx.x >> 6;
    int row = blockIdx.x * 4 + w;
    const float* xr = x + (size_t)row * 4096;

    // lane l owns column b=l: e[a] = X[a][l]  (64 coalesced 256B loads)
    float e[64];
#pragma unroll
    for (int a = 0; a < 64; ++a) e[a] = xr[a * 64 + l];

    h64(e);  // a-axis: element strides 2048..64, descending

    // transpose via LDS. Write vectorized with chunk rotation (t+l)&15:
    // phys[l*64 + 4*((t+l)&15) + j] = A[4t+j][l]; balanced bank groups.
    float* T = tile[w];
#pragma unroll
    for (int t = 0; t < 16; ++t) {
        float4v v;
        v[0] = e[4 * t + 0]; v[1] = e[4 * t + 1];
        v[2] = e[4 * t + 2]; v[3] = e[4 * t + 3];
        *(float4v*)(T + l * 64 + 4 * ((t + l) & 15)) = v;
    }
    __syncthreads();
    // lane l reads row a=l: A[l][b] at phys[b*64 + 4*(((l>>2)+b)&15) + (l&3)]
    // banks: per b, 64 lanes cover all 32 banks twice -> 2-way (free).
    {
        int t0 = l >> 2, j0 = l & 3;
#pragma unroll
        for (int b = 0; b < 64; ++b)
            e[b] = T[b * 64 + 4 * ((t0 + b) & 15) + j0];
    }

    h64(e);  // b-axis: element strides 32..1, descending

#pragma unroll
    for (int j = 0; j < 64; ++j) e[j] *= 0.015625f;  // 1/sqrt(4096), exact

    // lane l holds y[row][l*64 .. l*64+63]; 16 float4 stores (256B stride)
    float* yr = y + (size_t)row * 4096 + l * 64;
#pragma unroll
    for (int t = 0; t < 16; ++t) {
        float4v v;
        v[0] = e[4 * t + 0]; v[1] = e[4 * t + 1];
        v[2] = e[4 * t + 2]; v[3] = e[4 * t + 3];
        *(float4v*)(yr + 4 * t) = v;
    }

    float mn = e[0], mx = e[0];
#pragma unroll
    for (int j = 1; j < 64; ++j) { mn = fminf(mn, e[j]); mx = fmaxf(mx, e[j]); }
#pragma unroll
    for (int m = 32; m >= 1; m >>= 1) {
        mn = fminf(mn, __shfl_xor(mn, m));
        mx = fmaxf(mx, __shfl_xor(mx, m));
    }
    if (l == 0) wmm[row] = make_float2(mn, mx);
}

// ---- tiny deterministic reduction: 8192 wave-results -> global min/max ----
__global__ __launch_bounds__(1024) void k_mmred(const float2* __restrict__ wmm,
                                                float* __restrict__ mm) {
    __shared__ float red[32];
    int t = threadIdx.x;
    float mn = INFINITY, mx = -INFINITY;
#pragma unroll
    for (int i = t; i < 8192; i += 1024) {
        float2 v = wmm[i];
        mn = fminf(mn, v.x);
        mx = fmaxf(mx, v.y);
    }
#pragma unroll
    for (int m = 32; m >= 1; m >>= 1) {
        mn = fminf(mn, __shfl_xor(mn, m));
        mx = fmaxf(mx, __shfl_xor(mx, m));
    }
    if ((t & 63) == 0) { red[(t >> 6) * 2] = mn; red[(t >> 6) * 2 + 1] = mx; }
    __syncthreads();
    if (t == 0) {
#pragma unroll
        for (int wv = 1; wv < 16; ++wv) {
            mn = fminf(mn, red[wv * 2]);
            mx = fmaxf(mx, red[wv * 2 + 1]);
        }
        mm[0] = mn;
        mm[1] = mx;
    }
}

// ---- pass 2: streaming quantize y -> packed i8 codes (q - zp) ------------
__global__ __launch_bounds__(256) void k_quant_x(
    const float* __restrict__ y, const float* __restrict__ mm,
    int8_t* __restrict__ xq) {
    float xmin = mm[0], xmax = mm[1];
    float scale = fmaxf((xmax - xmin) / 15.0f, EPSQ);
    float zp = rintf(-xmin / scale);
    int izp = (int)zp;

    const float4v* yv = (const float4v*)y;
    int* q = (int*)xq;
    const size_t n4 = (size_t)8192 * 4096 / 4;
    const size_t stride = (size_t)4096 * 256;
    for (size_t i = (size_t)blockIdx.x * 256 + threadIdx.x; i < n4;
         i += stride) {
        float4v v = yv[i];
        int pk = 0;
#pragma unroll
        for (int r = 0; r < 4; ++r) {
            float qq = rintf(v[r] / scale) + zp;
            qq = fminf(fmaxf(qq, 0.0f), 15.0f);
            int code = (int)qq - izp;  // [-15,15]
            pk |= (code & 0xFF) << (8 * r);
        }
        q[i] = pk;
    }
}

// ---- weight quant: per-row absmax -> scale -> packed i8 ----
__global__ __launch_bounds__(256) void k_quant_w(
    const float* __restrict__ wgt, int8_t* __restrict__ wq,
    float* __restrict__ sw) {
    __shared__ float red[4];
    int o = blockIdx.x, t = threadIdx.x;
    const float4v* wv = (const float4v*)(wgt + (size_t)o * 4096);
    float4v a0 = wv[t * 4 + 0], a1 = wv[t * 4 + 1],
            a2 = wv[t * 4 + 2], a3 = wv[t * 4 + 3];
    float am = 0.0f;
#pragma unroll
    for (int r = 0; r < 4; ++r)
        am = fmaxf(am, fmaxf(fmaxf(fabsf(a0[r]), fabsf(a1[r])),
                             fmaxf(fabsf(a2[r]), fabsf(a3[r]))));
#pragma unroll
    for (int m = 32; m >= 1; m >>= 1) am = fmaxf(am, __shfl_xor(am, m));
    if ((t & 63) == 0) red[t >> 6] = am;
    __syncthreads();
    am = fmaxf(fmaxf(red[0], red[1]), fmaxf(red[2], red[3]));

    float scale = fmaxf(am / 7.0f, EPSQ);
    if (t == 0) sw[o] = scale;

    int4v pk;
#pragma unroll
    for (int k = 0; k < 4; ++k) {
        float4v a = (k == 0) ? a0 : (k == 1) ? a1 : (k == 2) ? a2 : a3;
        int p = 0;
#pragma unroll
        for (int r = 0; r < 4; ++r) {
            float q = rintf(a[r] / scale);
            q = fminf(fmaxf(q, -8.0f), 7.0f);
            p |= ((int)q & 0xFF) << (8 * r);
        }
        pk[k] = p;
    }
    *(int4v*)(wq + (size_t)o * 4096 + t * 16) = pk;
}

// ---------------- i8 GEMM, m97 structure + LDS XOR swizzle ----------------
// R7 verified: SQ_LDS_BANK_CONFLICT == 0 with this swizzle.
#define BM 128
#define BN 128
#define BKq 64

__global__ __launch_bounds__(256) void k_gemm(
    const int8_t* __restrict__ A,   // [8192][4096] qx-zp
    const int8_t* __restrict__ B,   // [4096][4096] qw (N x K)
    const float* __restrict__ sw, const float* __restrict__ bias,
    const float* __restrict__ mm, float* __restrict__ C) {
    constexpr int N = 4096, K = 4096;
    __shared__ __align__(16) int8_t As[BM * BKq];
    __shared__ __align__(16) int8_t Bs[BN * BKq];

    int tid = threadIdx.x;
    int m0 = (blockIdx.x >> 5) * BM;
    int n0 = (blockIdx.x & 31) * BN;
    int w = tid >> 6, l = tid & 63;
    int wr = w >> 1, wc = w & 1;  // wave -> 64x64 quadrant
    int kg = l >> 4, lr = l & 15;

    int4v acc[4][4] = {};

    for (int k0 = 0; k0 < K; k0 += BKq) {
#pragma unroll
        for (int it = 0; it < 2; ++it) {
            int idx = it * 256 + tid;
            int row = idx >> 2;
            int ccs = (idx & 3) ^ ((row >> 1) & 3);  // pre-swizzled source
            __builtin_amdgcn_global_load_lds(
                (const __attribute__((address_space(1))) void*)
                    (A + (size_t)(m0 + row) * K + k0 + ccs * 16),
                (__attribute__((address_space(3))) void*)(As + idx * 16),
                16, 0, 0);
            __builtin_amdgcn_global_load_lds(
                (const __attribute__((address_space(1))) void*)
                    (B + (size_t)(n0 + row) * K + k0 + ccs * 16),
                (__attribute__((address_space(3))) void*)(Bs + idx * 16),
                16, 0, 0);
        }
        __syncthreads();

        int4v af[4], bf[4];
#pragma unroll
        for (int i = 0; i < 4; ++i) {
            int ra = wr * 64 + i * 16 + lr;
            int rb = wc * 64 + i * 16 + lr;
            af[i] = *(const int4v*)(As + ra * BKq +
                                    ((kg ^ ((ra >> 1) & 3)) * 16));
            bf[i] = *(const int4v*)(Bs + rb * BKq +
                                    ((kg ^ ((rb >> 1) & 3)) * 16));
        }
#pragma unroll
        for (int i = 0; i < 4; ++i)
#pragma unroll
            for (int j = 0; j < 4; ++j)
                acc[i][j] = __builtin_amdgcn_mfma_i32_16x16x64_i8(
                    af[i], bf[j], acc[i][j], 0, 0, 0);
        __syncthreads();
    }

    float xmin = mm[0], xmax = mm[1];
    float sx = fmaxf((xmax - xmin) / 15.0f, EPSQ);

#pragma unroll
    for (int j = 0; j < 4; ++j) {
        int col = n0 + wc * 64 + j * 16 + lr;
        float s = sx * sw[col];
        float bz = bias[col];
#pragma unroll
        for (int i = 0; i < 4; ++i) {
            int rowb = m0 + wr * 64 + i * 16 + kg * 4;
#pragma unroll
            for (int r = 0; r < 4; ++r)
                C[(size_t)(rowb + r) * N + col] =
                    (float)acc[i][j][r] * s + bz;
        }
    }
}

extern "C" void kernel_launch(void* const* d_in, const int* in_sizes, int n_in,
                              void* d_out, int out_size, void* d_ws,
                              size_t ws_size, hipStream_t stream) {
    const float* x = (const float*)d_in[0];       // [4,2048,4096]
    const float* weight = (const float*)d_in[1];  // [4096,4096]
    const float* bias = (const float*)d_in[2];    // [4096]
    float* out = (float*)d_out;

    char* ws = (char*)d_ws;
    float* mm = (float*)ws;                            // 8 B  {min,max}
    float2* wmm = (float2*)(ws + 1024);                // 64 KB per-wave pairs
    float* sw = (float*)(ws + 131072);                 // 16 KB
    int8_t* xq = (int8_t*)(ws + (1 << 20));            // 32 MB
    int8_t* wq = (int8_t*)(ws + (1 << 20) + ((size_t)8192 * 4096));  // 16 MB

    // d_out doubles as the fp32 y buffer (exactly 8192*4096 floats):
    // written by k_fwht, read by k_quant_x, then overwritten by k_gemm.
    float* y = out;

    hipLaunchKernelGGL(k_fwht, dim3(2048), dim3(256), 0, stream, x, y, wmm);
    hipLaunchKernelGGL(k_mmred, dim3(1), dim3(1024), 0, stream, wmm, mm);
    hipLaunchKernelGGL(k_quant_w, dim3(4096), dim3(256), 0, stream,
                       weight, wq, sw);
    hipLaunchKernelGGL(k_quant_x, dim3(4096), dim3(256), 0, stream,
                       y, mm, xq);
    hipLaunchKernelGGL(k_gemm, dim3(64 * 32), dim3(256), 0, stream,
                       xq, wq, sw, bias, mm, out);
}